// Round 6
// baseline (5998.206 us; speedup 1.0000x reference)
//
#include <hip/hip_runtime.h>

// DRL4TSP pointer-network decode. B=1024, S=2, D=1, H=128, N=128.
// Rank-collapse algebra: static_enc rank-2+bias, dynamic_enc rank-1+bias =>
// all per-step GEMMs become precomputed H-vectors + w_hh@h, A3@h matvecs +
// two HxN tanh-dot loops.
//
// R6: R5 ran ~5x above the issue floor -> stalled on per-step L2 weight
// streams (WT 192KB + AT 64KB per block per step, 2 waves/SIMD, loads in
// unroll-4 groups). Fixes: (1) full unroll of P1/P2 load loops (deep
// in-flight pipelining) + balanced P1 (all 4 waves do 1.5 rows; n-gate dot
// split across wave pairs); (2) tables pre-scaled by 2*log2e so score tanh
// is 4 ops (exp2, add, rcp, fma) with saturation handling overflow;
// (3) attention softmax without max-subtract (|score|<=28, exp can't
// overflow fp32); P4 keeps max (it IS the argmax).

#define H128 128
#define N128 128
#define B1024 1024
#define SC 2.885390081777927f   // 2*log2(e): tanh(x) = 1 - 2/(exp2(SC*x)+1)

__device__ __forceinline__ float sigmoid_acc(float x){
    return 1.f / (1.f + expf(-x));
}
// pre-scaled fast tanh: input already multiplied by SC (folded into tables).
// exp2(+inf)->inf -> rcp->0 -> +1; exp2(-big)->0 -> rcp(1)=1 -> -1. No clamp.
__device__ __forceinline__ float tanh_ps(float xs){
    float e = exp2f(xs);                         // v_exp_f32
    float r = __builtin_amdgcn_rcpf(e + 1.f);    // v_rcp_f32
    return fmaf(-2.f, r, 1.f);
}

// ---------------- prep: fold rank structure into packed tables ----------------
// ws floats: A4[512]@0, D4[512]@512, Q4[512]@1024, G4[1536]@1536,
//            WT[49152]@3072 (w_hh^T: WT[k*384+r]), AT[16384]@52224 (SC*A3^T)
// A4[h] = {SC*u0, SC*u1, SC*u2, attn_v[h]}   D4[h] = {SC*v0, SC*v1, dec_v[h], 0}
// Q4[h] = {SC*q0, SC*q1, SC*c2, SC*c1}       G4[j] = {g0, g1, gc, b_hh[j]}
__global__ void prep_kernel(const float* __restrict__ enc_s_w, const float* __restrict__ enc_s_b,
                            const float* __restrict__ enc_d_w, const float* __restrict__ enc_d_b,
                            const float* __restrict__ emb_w,   const float* __restrict__ emb_b,
                            const float* __restrict__ w_ih,    const float* __restrict__ b_ih,
                            const float* __restrict__ b_hh,
                            const float* __restrict__ attn_v,  const float* __restrict__ attn_W,
                            const float* __restrict__ dec_v,   const float* __restrict__ dec_W,
                            float4* __restrict__ A4, float4* __restrict__ D4,
                            float4* __restrict__ Q4, float4* __restrict__ G4)
{
    const int tid = threadIdx.x;
    const int blk = blockIdx.x;
    if (blk < 3){
        const int j = blk*128 + tid;
        const float* w = w_ih + j*H128;
        float a = 0.f, b = 0.f, c = 0.f;
        for (int k = 0; k < H128; ++k){
            float wv = w[k];
            a = fmaf(wv, emb_w[2*k],   a);
            b = fmaf(wv, emb_w[2*k+1], b);
            c = fmaf(wv, emb_b[k],     c);
        }
        G4[j] = make_float4(a, b, c + b_ih[j], b_hh[j]);
    } else {
        const int h = tid;
        const float* aw = attn_W + h*384;
        float u0=0.f, u1=0.f, u2=0.f, c1=0.f;
        for (int k = 0; k < H128; ++k){
            float w = aw[k];
            u0 = fmaf(w, enc_s_w[2*k],   u0);
            u1 = fmaf(w, enc_s_w[2*k+1], u1);
            c1 = fmaf(w, enc_s_b[k],     c1);
        }
        for (int k = 0; k < H128; ++k){
            float w = aw[128+k];
            u2 = fmaf(w, enc_d_w[k], u2);
            c1 = fmaf(w, enc_d_b[k], c1);
        }
        A4[h] = make_float4(SC*u0, SC*u1, SC*u2, attn_v[h]);
        const float* dw = dec_W + h*256;
        float v0=0.f, v1=0.f, c2=0.f, q0=0.f, q1=0.f;
        for (int k = 0; k < H128; ++k){
            float w = dw[k];
            v0 = fmaf(w, enc_s_w[2*k],   v0);
            v1 = fmaf(w, enc_s_w[2*k+1], v1);
            c2 = fmaf(w, enc_s_b[k],     c2);
        }
        for (int k = 0; k < H128; ++k){
            float w = dw[128+k];
            q0 = fmaf(w, enc_s_w[2*k],   q0);
            q1 = fmaf(w, enc_s_w[2*k+1], q1);
            c2 = fmaf(w, enc_s_b[k],     c2);   // ctx bias == enc_s_b (sum attn == 1)
        }
        D4[h] = make_float4(SC*v0, SC*v1, dec_v[h], 0.f);
        Q4[h] = make_float4(SC*q0, SC*q1, SC*c2, SC*c1);
    }
}

// one-time weight transpose (AT pre-scaled by SC)
__global__ void tp_kernel(const float* __restrict__ whh, const float* __restrict__ attnW,
                          float* __restrict__ WT, float* __restrict__ AT)
{
    const int idx = blockIdx.x*256 + threadIdx.x;
    if (idx < 49152){
        const int k = idx / 384, r = idx - k*384;   // WT[k][r] = whh[r][k]
        WT[idx] = whh[r*H128 + k];
    } else {
        const int i2 = idx - 49152;                  // AT[k][j] = SC*attn_W[j][256+k]
        const int k = i2 >> 7, j = i2 & 127;
        AT[i2] = SC * attnW[j*384 + 256 + k];
    }
}

// ---------------- main decode: one block = 2 batches, 256 threads ----------------
__global__ __launch_bounds__(256, 2)
void decode_kernel(const float* __restrict__ statc, const float* __restrict__ dyn,
                   const float* __restrict__ x0,
                   const float* __restrict__ WT, const float* __restrict__ AT,
                   const float4* __restrict__ A4g, const float4* __restrict__ D4g,
                   const float4* __restrict__ Q4g, const float4* __restrict__ G4g,
                   float* __restrict__ out)
{
    __shared__ __align__(16) float hbuf[2][2][H128];   // [pingpong][g][h]
    __shared__ float gpre[2][5][H128];                 // [g][r,z,nA,gin,nB][j]
    __shared__ __align__(16) float ahl[2][H128], chl[2][H128];
    __shared__ float s0l[2][N128], s1l[2][N128];
    __shared__ float red[2][2][8];

    const int tid = threadIdx.x;
    const int g   = tid >> 7;         // batch within block (phases 2-4)
    const int jl  = tid & 127;        // h-row / n-column owned by this thread
    const int wv  = (tid >> 6) & 1;   // wave within the g-half
    const int b   = blockIdx.x*2 + g;

    // P1 assignment: every thread does row tid fully (r rows for tid<128,
    // z rows otherwise) + HALF of n-row (256+j1): waves 0-1 k[0:64), waves 2-3 k[64:128).
    const int  gate1 = tid >> 7;
    const int  j1    = tid & 127;
    const bool loA   = (tid < 128);
    const float4 Gv1 = G4g[tid];
    const float4 Gv2 = G4g[256 + j1];

    const float4 qv = Q4g[jl];
    const float q0r = qv.x, q1r = qv.y, c2r = qv.z, c1r = qv.w;

    const float s0n = statc[b*256 + jl];
    const float s1n = statc[b*256 + 128 + jl];
    const float d0n = dyn[b*128 + jl];
    s0l[g][jl] = s0n; s1l[g][jl] = s1n;
    hbuf[0][g][jl] = 0.f;
    float hreg = 0.f;
    float l00 = x0[0], l01 = x0[1];   // last_out, batch 0 (all threads track both)
    float l10 = l00,   l11 = l01;     // last_out, batch 1

    float logp = 0.f;
    int cur = 0;
    __syncthreads();

    for (int t = 0; t < N128; ++t){
        // ---- phase 1: gh = w_hh@h, transposed/coalesced, fully unrolled ----
        const float4* h0v = (const float4*)&hbuf[cur][0][0];
        const float4* h1v = (const float4*)&hbuf[cur][1][0];
        {   // own gate row (full 128-k dot, both batches)
            const float* pW = WT + tid;
            float a0 = 0.f, a1 = 0.f;
            #pragma unroll
            for (int k4 = 0; k4 < 32; ++k4){
                float4 h0 = h0v[k4], h1 = h1v[k4];
                float w0 = pW[(4*k4+0)*384];
                float w1 = pW[(4*k4+1)*384];
                float w2 = pW[(4*k4+2)*384];
                float w3 = pW[(4*k4+3)*384];
                a0 = fmaf(w0,h0.x, fmaf(w1,h0.y, fmaf(w2,h0.z, fmaf(w3,h0.w, a0))));
                a1 = fmaf(w0,h1.x, fmaf(w1,h1.y, fmaf(w2,h1.z, fmaf(w3,h1.w, a1))));
            }
            float gi0 = fmaf(Gv1.x, l00, fmaf(Gv1.y, l01, Gv1.z));
            float gi1 = fmaf(Gv1.x, l10, fmaf(Gv1.y, l11, Gv1.z));
            gpre[0][gate1][j1] = gi0 + (a0 + Gv1.w);
            gpre[1][gate1][j1] = gi1 + (a1 + Gv1.w);
        }
        {   // half n-row (64-k dot, both batches)
            const float* pW = WT + 256 + j1;
            const int koff = gate1 * 16;     // k4 offset 0 or 16
            float a0 = 0.f, a1 = 0.f;
            #pragma unroll
            for (int ki = 0; ki < 16; ++ki){
                const int k4 = koff + ki;
                float4 h0 = h0v[k4], h1 = h1v[k4];
                float w0 = pW[(4*k4+0)*384];
                float w1 = pW[(4*k4+1)*384];
                float w2 = pW[(4*k4+2)*384];
                float w3 = pW[(4*k4+3)*384];
                a0 = fmaf(w0,h0.x, fmaf(w1,h0.y, fmaf(w2,h0.z, fmaf(w3,h0.w, a0))));
                a1 = fmaf(w0,h1.x, fmaf(w1,h1.y, fmaf(w2,h1.z, fmaf(w3,h1.w, a1))));
            }
            if (loA){
                gpre[0][2][j1] = a0 + Gv2.w;
                gpre[1][2][j1] = a1 + Gv2.w;
                gpre[0][3][j1] = fmaf(Gv2.x, l00, fmaf(Gv2.y, l01, Gv2.z));
                gpre[1][3][j1] = fmaf(Gv2.x, l10, fmaf(Gv2.y, l11, Gv2.z));
            } else {
                gpre[0][4][j1] = a0;
                gpre[1][4][j1] = a1;
            }
        }
        __syncthreads();                           // B1: gate partials visible
        // combine: thread (g, jl) computes hnew[g][jl]. libm numerics on h path.
        {
            float r  = sigmoid_acc(gpre[g][0][jl]);
            float z  = sigmoid_acc(gpre[g][1][jl]);
            float accn = gpre[g][2][jl] + gpre[g][4][jl];
            float nn = tanhf(gpre[g][3][jl] + r * accn);
            float hnew = (1.f - z) * nn + z * hreg;
            hbuf[cur^1][g][jl] = hnew; hreg = hnew;
        }
        __syncthreads();                           // B2: new h visible
        cur ^= 1;
        // ---- phase 2: ah = SC*(A3@h + c1), transposed/coalesced, full unroll ----
        {
            const float4* hn4 = (const float4*)&hbuf[cur][g][0];
            const float* pA = AT + jl;
            float acc = c1r;
            #pragma unroll
            for (int k4 = 0; k4 < 32; ++k4){
                float4 hv = hn4[k4];
                acc = fmaf(pA[(4*k4+0)*128], hv.x, acc);
                acc = fmaf(pA[(4*k4+1)*128], hv.y, acc);
                acc = fmaf(pA[(4*k4+2)*128], hv.z, acc);
                acc = fmaf(pA[(4*k4+3)*128], hv.w, acc);
            }
            ahl[g][jl] = acc;
        }
        __syncthreads();                           // B3: ahl visible
        // ---- phase 3: attention scores; no-max softmax (|sc| <= ~28) ----
        const float4* ah4 = (const float4*)&ahl[g][0];
        float sc = 0.f;
        #pragma unroll 2
        for (int k = 0; k < 32; ++k){
            float4 ah = ah4[k];
            { float4 a = A4g[4*k+0]; float tt = fmaf(a.x,s0n, fmaf(a.y,s1n, fmaf(a.z,d0n, ah.x))); sc = fmaf(tanh_ps(tt), a.w, sc); }
            { float4 a = A4g[4*k+1]; float tt = fmaf(a.x,s0n, fmaf(a.y,s1n, fmaf(a.z,d0n, ah.y))); sc = fmaf(tanh_ps(tt), a.w, sc); }
            { float4 a = A4g[4*k+2]; float tt = fmaf(a.x,s0n, fmaf(a.y,s1n, fmaf(a.z,d0n, ah.z))); sc = fmaf(tanh_ps(tt), a.w, sc); }
            { float4 a = A4g[4*k+3]; float tt = fmaf(a.x,s0n, fmaf(a.y,s1n, fmaf(a.z,d0n, ah.w))); sc = fmaf(tanh_ps(tt), a.w, sc); }
        }
        float e  = __expf(sc);
        float se = e, sa = e * s0n, sb = e * s1n;
        #pragma unroll
        for (int off = 32; off > 0; off >>= 1){
            se += __shfl_xor(se, off, 64);
            sa += __shfl_xor(sa, off, 64);
            sb += __shfl_xor(sb, off, 64);
        }
        if ((tid & 63) == 0){ red[g][wv][0]=se; red[g][wv][1]=sa; red[g][wv][2]=sb; }
        __syncthreads();                           // B4: attn partials visible
        {
            float ssum = red[g][0][0] + red[g][1][0];
            float sat  = red[g][0][1] + red[g][1][1];
            float sbt  = red[g][0][2] + red[g][1][2];
            float cs0 = sat / ssum;
            float cs1 = sbt / ssum;
            chl[g][jl] = fmaf(q0r, cs0, fmaf(q1r, cs1, c2r));   // SC*(dec_W2@context fold)
        }
        __syncthreads();                           // B5: chl visible
        // ---- phase 4: decoder scores + argmax + logsumexp ----
        const float4* ch4 = (const float4*)&chl[g][0];
        float lg = 0.f;
        #pragma unroll 2
        for (int k = 0; k < 32; ++k){
            float4 ch = ch4[k];
            { float4 dd = D4g[4*k+0]; float tt = fmaf(dd.x,s0n, fmaf(dd.y,s1n, ch.x)); lg = fmaf(tanh_ps(tt), dd.z, lg); }
            { float4 dd = D4g[4*k+1]; float tt = fmaf(dd.x,s0n, fmaf(dd.y,s1n, ch.y)); lg = fmaf(tanh_ps(tt), dd.z, lg); }
            { float4 dd = D4g[4*k+2]; float tt = fmaf(dd.x,s0n, fmaf(dd.y,s1n, ch.z)); lg = fmaf(tanh_ps(tt), dd.z, lg); }
            { float4 dd = D4g[4*k+3]; float tt = fmaf(dd.x,s0n, fmaf(dd.y,s1n, ch.w)); lg = fmaf(tanh_ps(tt), dd.z, lg); }
        }
        float v = lg; int bi = jl;
        #pragma unroll
        for (int off = 32; off > 0; off >>= 1){   // first-index tie-break == jnp.argmax
            float ov = __shfl_xor(v, off, 64);
            int   oi = __shfl_xor(bi, off, 64);
            if (ov > v || (ov == v && oi < bi)){ v = ov; bi = oi; }
        }
        float e2 = __expf(lg - v);
        #pragma unroll
        for (int off = 32; off > 0; off >>= 1) e2 += __shfl_xor(e2, off, 64);
        if ((tid & 63) == 0){ red[g][wv][4]=v; red[g][wv][5]=__int_as_float(bi); red[g][wv][6]=e2; }
        __syncthreads();                           // B6: argmax partials visible
        int ptrs[2];
        #pragma unroll
        for (int gg = 0; gg < 2; ++gg){
            float va = red[gg][0][4], vb = red[gg][1][4];
            int   ia = __float_as_int(red[gg][0][5]), ib = __float_as_int(red[gg][1][5]);
            ptrs[gg] = (va > vb || (va == vb && ia < ib)) ? ia : ib;
        }
        {   // own-batch logp
            float va = red[g][0][4], vb = red[g][1][4];
            int   ia = __float_as_int(red[g][0][5]), ib = __float_as_int(red[g][1][5]);
            float s2a = red[g][0][6], s2b = red[g][1][6];
            float m2; int ptr;
            if (va > vb || (va == vb && ia < ib)){ m2 = va; ptr = ia; } else { m2 = vb; ptr = ib; }
            float sum2 = fmaf(s2a, __expf(va - m2), s2b * __expf(vb - m2));
            logp -= logf(sum2);
            if (jl == 0) out[b*N128 + t] = (float)ptr;
        }
        l00 = s0l[0][ptrs[0]]; l01 = s1l[0][ptrs[0]];
        l10 = s0l[1][ptrs[1]]; l11 = s1l[1][ptrs[1]];
    }
    if (jl == 0) out[B1024*N128 + b] = logp;
}

extern "C" void kernel_launch(void* const* d_in, const int* in_sizes, int n_in,
                              void* d_out, int out_size, void* d_ws, size_t ws_size,
                              hipStream_t stream)
{
    const float* statc   = (const float*)d_in[0];
    const float* dyn     = (const float*)d_in[1];
    const float* enc_s_w = (const float*)d_in[2];
    const float* enc_s_b = (const float*)d_in[3];
    const float* enc_d_w = (const float*)d_in[4];
    const float* enc_d_b = (const float*)d_in[5];
    const float* x0      = (const float*)d_in[6];
    const float* emb_w   = (const float*)d_in[7];
    const float* emb_b   = (const float*)d_in[8];
    const float* w_ih    = (const float*)d_in[9];
    const float* w_hh    = (const float*)d_in[10];
    const float* b_ih    = (const float*)d_in[11];
    const float* b_hh    = (const float*)d_in[12];
    const float* attn_v  = (const float*)d_in[13];
    const float* attn_W  = (const float*)d_in[14];
    const float* dec_v   = (const float*)d_in[15];
    const float* dec_W   = (const float*)d_in[16];

    float* ws = (float*)d_ws;
    float4* A4 = (float4*)(ws);
    float4* D4 = (float4*)(ws + 512);
    float4* Q4 = (float4*)(ws + 1024);
    float4* G4 = (float4*)(ws + 1536);
    float*  WT = ws + 3072;            // [128][384]
    float*  AT = ws + 3072 + 49152;    // [128][128], pre-scaled by SC

    prep_kernel<<<dim3(4), dim3(128), 0, stream>>>(
        enc_s_w, enc_s_b, enc_d_w, enc_d_b, emb_w, emb_b,
        w_ih, b_ih, b_hh, attn_v, attn_W, dec_v, dec_W,
        A4, D4, Q4, G4);

    tp_kernel<<<dim3(256), dim3(256), 0, stream>>>(w_hh, attn_W, WT, AT);

    decode_kernel<<<dim3(B1024/2), dim3(256), 0, stream>>>(
        statc, dyn, x0, WT, AT,
        A4, D4, Q4, G4, (float*)d_out);
}

// Round 8
// 2755.372 us; speedup vs baseline: 2.1769x; 2.1769x over previous
//
#include <hip/hip_runtime.h>

// DRL4TSP pointer-network decode. B=1024, S=2, D=1, H=128, N=128.
// Rank-collapse algebra: static_enc rank-2+bias, dynamic_enc rank-1+bias =>
// all big per-step GEMMs become precomputed H-vectors + w_hh@h, A3@h matvecs
// + two HxN tanh-dot loops.
//
// R7 = R6 minus the full unroll (resubmitted R8; R7 attempt hit GPU-acquisition
// timeout). R6's #pragma unroll on the 128/64-load weight loops blew VGPRs
// 60->128, spilled to scratch, and the per-step scratch rewrite thrashed L2
// (FETCH 1.9MB -> 4.4GB, WRITE 528KB -> 75MB). Reverting to unroll-4 restores
// R5's cache-resident behavior. KEPT from R6 (all validated by R6's
// absmax=0.0): pre-scaled 4-op tanh_ps, SC-folded tables, no-max attention
// softmax, balanced P1 (all 4 waves do 1.5 rows).

#define H128 128
#define N128 128
#define B1024 1024
#define SC 2.885390081777927f   // 2*log2(e): tanh(x) = 1 - 2/(exp2(SC*x)+1)

__device__ __forceinline__ float sigmoid_acc(float x){
    return 1.f / (1.f + expf(-x));
}
// pre-scaled fast tanh: input already multiplied by SC (folded into tables).
// exp2(+inf)->inf -> rcp->0 -> +1; exp2(-big)->0 -> rcp(1)=1 -> -1. No clamp.
__device__ __forceinline__ float tanh_ps(float xs){
    float e = exp2f(xs);                         // v_exp_f32
    float r = __builtin_amdgcn_rcpf(e + 1.f);    // v_rcp_f32
    return fmaf(-2.f, r, 1.f);
}

// ---------------- prep: fold rank structure into packed tables ----------------
// ws floats: A4[512]@0, D4[512]@512, Q4[512]@1024, G4[1536]@1536,
//            WT[49152]@3072 (w_hh^T: WT[k*384+r]), AT[16384]@52224 (SC*A3^T)
// A4[h] = {SC*u0, SC*u1, SC*u2, attn_v[h]}   D4[h] = {SC*v0, SC*v1, dec_v[h], 0}
// Q4[h] = {SC*q0, SC*q1, SC*c2, SC*c1}       G4[j] = {g0, g1, gc, b_hh[j]}
__global__ void prep_kernel(const float* __restrict__ enc_s_w, const float* __restrict__ enc_s_b,
                            const float* __restrict__ enc_d_w, const float* __restrict__ enc_d_b,
                            const float* __restrict__ emb_w,   const float* __restrict__ emb_b,
                            const float* __restrict__ w_ih,    const float* __restrict__ b_ih,
                            const float* __restrict__ b_hh,
                            const float* __restrict__ attn_v,  const float* __restrict__ attn_W,
                            const float* __restrict__ dec_v,   const float* __restrict__ dec_W,
                            float4* __restrict__ A4, float4* __restrict__ D4,
                            float4* __restrict__ Q4, float4* __restrict__ G4)
{
    const int tid = threadIdx.x;
    const int blk = blockIdx.x;
    if (blk < 3){
        const int j = blk*128 + tid;
        const float* w = w_ih + j*H128;
        float a = 0.f, b = 0.f, c = 0.f;
        for (int k = 0; k < H128; ++k){
            float wv = w[k];
            a = fmaf(wv, emb_w[2*k],   a);
            b = fmaf(wv, emb_w[2*k+1], b);
            c = fmaf(wv, emb_b[k],     c);
        }
        G4[j] = make_float4(a, b, c + b_ih[j], b_hh[j]);
    } else {
        const int h = tid;
        const float* aw = attn_W + h*384;
        float u0=0.f, u1=0.f, u2=0.f, c1=0.f;
        for (int k = 0; k < H128; ++k){
            float w = aw[k];
            u0 = fmaf(w, enc_s_w[2*k],   u0);
            u1 = fmaf(w, enc_s_w[2*k+1], u1);
            c1 = fmaf(w, enc_s_b[k],     c1);
        }
        for (int k = 0; k < H128; ++k){
            float w = aw[128+k];
            u2 = fmaf(w, enc_d_w[k], u2);
            c1 = fmaf(w, enc_d_b[k], c1);
        }
        A4[h] = make_float4(SC*u0, SC*u1, SC*u2, attn_v[h]);
        const float* dw = dec_W + h*256;
        float v0=0.f, v1=0.f, c2=0.f, q0=0.f, q1=0.f;
        for (int k = 0; k < H128; ++k){
            float w = dw[k];
            v0 = fmaf(w, enc_s_w[2*k],   v0);
            v1 = fmaf(w, enc_s_w[2*k+1], v1);
            c2 = fmaf(w, enc_s_b[k],     c2);
        }
        for (int k = 0; k < H128; ++k){
            float w = dw[128+k];
            q0 = fmaf(w, enc_s_w[2*k],   q0);
            q1 = fmaf(w, enc_s_w[2*k+1], q1);
            c2 = fmaf(w, enc_s_b[k],     c2);   // ctx bias == enc_s_b (sum attn == 1)
        }
        D4[h] = make_float4(SC*v0, SC*v1, dec_v[h], 0.f);
        Q4[h] = make_float4(SC*q0, SC*q1, SC*c2, SC*c1);
    }
}

// one-time weight transpose (AT pre-scaled by SC)
__global__ void tp_kernel(const float* __restrict__ whh, const float* __restrict__ attnW,
                          float* __restrict__ WT, float* __restrict__ AT)
{
    const int idx = blockIdx.x*256 + threadIdx.x;
    if (idx < 49152){
        const int k = idx / 384, r = idx - k*384;   // WT[k][r] = whh[r][k]
        WT[idx] = whh[r*H128 + k];
    } else {
        const int i2 = idx - 49152;                  // AT[k][j] = SC*attn_W[j][256+k]
        const int k = i2 >> 7, j = i2 & 127;
        AT[i2] = SC * attnW[j*384 + 256 + k];
    }
}

// ---------------- main decode: one block = 2 batches, 256 threads ----------------
__global__ __launch_bounds__(256, 2)
void decode_kernel(const float* __restrict__ statc, const float* __restrict__ dyn,
                   const float* __restrict__ x0,
                   const float* __restrict__ WT, const float* __restrict__ AT,
                   const float4* __restrict__ A4g, const float4* __restrict__ D4g,
                   const float4* __restrict__ Q4g, const float4* __restrict__ G4g,
                   float* __restrict__ out)
{
    __shared__ __align__(16) float hbuf[2][2][H128];   // [pingpong][g][h]
    __shared__ float gpre[2][5][H128];                 // [g][r,z,nA,gin,nB][j]
    __shared__ __align__(16) float ahl[2][H128], chl[2][H128];
    __shared__ float s0l[2][N128], s1l[2][N128];
    __shared__ float red[2][2][8];

    const int tid = threadIdx.x;
    const int g   = tid >> 7;         // batch within block (phases 2-4)
    const int jl  = tid & 127;        // h-row / n-column owned by this thread
    const int wv  = (tid >> 6) & 1;   // wave within the g-half
    const int b   = blockIdx.x*2 + g;

    // P1 assignment: every thread does row tid fully (r rows for tid<128,
    // z rows otherwise) + HALF of n-row (256+j1): waves 0-1 k[0:64), waves 2-3 k[64:128).
    const int  gate1 = tid >> 7;
    const int  j1    = tid & 127;
    const bool loA   = (tid < 128);
    const float4 Gv1 = G4g[tid];
    const float4 Gv2 = G4g[256 + j1];

    const float4 qv = Q4g[jl];
    const float q0r = qv.x, q1r = qv.y, c2r = qv.z, c1r = qv.w;

    const float s0n = statc[b*256 + jl];
    const float s1n = statc[b*256 + 128 + jl];
    const float d0n = dyn[b*128 + jl];
    s0l[g][jl] = s0n; s1l[g][jl] = s1n;
    hbuf[0][g][jl] = 0.f;
    float hreg = 0.f;
    float l00 = x0[0], l01 = x0[1];   // last_out, batch 0 (all threads track both)
    float l10 = l00,   l11 = l01;     // last_out, batch 1

    float logp = 0.f;
    int cur = 0;
    __syncthreads();

    for (int t = 0; t < N128; ++t){
        // ---- phase 1: gh = w_hh@h, transposed/coalesced, unroll 4 (NOT full:
        // full unroll spilled to scratch and thrashed L2 -- R6 post-mortem) ----
        const float4* h0v = (const float4*)&hbuf[cur][0][0];
        const float4* h1v = (const float4*)&hbuf[cur][1][0];
        {   // own gate row (full 128-k dot, both batches)
            const float* pW = WT + tid;
            float a0 = 0.f, a1 = 0.f;
            #pragma unroll 4
            for (int k4 = 0; k4 < 32; ++k4){
                float4 h0 = h0v[k4], h1 = h1v[k4];
                float w0 = pW[(4*k4+0)*384];
                float w1 = pW[(4*k4+1)*384];
                float w2 = pW[(4*k4+2)*384];
                float w3 = pW[(4*k4+3)*384];
                a0 = fmaf(w0,h0.x, fmaf(w1,h0.y, fmaf(w2,h0.z, fmaf(w3,h0.w, a0))));
                a1 = fmaf(w0,h1.x, fmaf(w1,h1.y, fmaf(w2,h1.z, fmaf(w3,h1.w, a1))));
            }
            float gi0 = fmaf(Gv1.x, l00, fmaf(Gv1.y, l01, Gv1.z));
            float gi1 = fmaf(Gv1.x, l10, fmaf(Gv1.y, l11, Gv1.z));
            gpre[0][gate1][j1] = gi0 + (a0 + Gv1.w);
            gpre[1][gate1][j1] = gi1 + (a1 + Gv1.w);
        }
        {   // half n-row (64-k dot, both batches)
            const float* pW = WT + 256 + j1;
            const int koff = gate1 * 16;     // k4 offset 0 or 16
            float a0 = 0.f, a1 = 0.f;
            #pragma unroll 4
            for (int ki = 0; ki < 16; ++ki){
                const int k4 = koff + ki;
                float4 h0 = h0v[k4], h1 = h1v[k4];
                float w0 = pW[(4*k4+0)*384];
                float w1 = pW[(4*k4+1)*384];
                float w2 = pW[(4*k4+2)*384];
                float w3 = pW[(4*k4+3)*384];
                a0 = fmaf(w0,h0.x, fmaf(w1,h0.y, fmaf(w2,h0.z, fmaf(w3,h0.w, a0))));
                a1 = fmaf(w0,h1.x, fmaf(w1,h1.y, fmaf(w2,h1.z, fmaf(w3,h1.w, a1))));
            }
            if (loA){
                gpre[0][2][j1] = a0 + Gv2.w;
                gpre[1][2][j1] = a1 + Gv2.w;
                gpre[0][3][j1] = fmaf(Gv2.x, l00, fmaf(Gv2.y, l01, Gv2.z));
                gpre[1][3][j1] = fmaf(Gv2.x, l10, fmaf(Gv2.y, l11, Gv2.z));
            } else {
                gpre[0][4][j1] = a0;
                gpre[1][4][j1] = a1;
            }
        }
        __syncthreads();                           // B1: gate partials visible
        // combine: thread (g, jl) computes hnew[g][jl]. libm numerics on h path.
        {
            float r  = sigmoid_acc(gpre[g][0][jl]);
            float z  = sigmoid_acc(gpre[g][1][jl]);
            float accn = gpre[g][2][jl] + gpre[g][4][jl];
            float nn = tanhf(gpre[g][3][jl] + r * accn);
            float hnew = (1.f - z) * nn + z * hreg;
            hbuf[cur^1][g][jl] = hnew; hreg = hnew;
        }
        __syncthreads();                           // B2: new h visible
        cur ^= 1;
        // ---- phase 2: ah = SC*(A3@h + c1), transposed/coalesced, unroll 4 ----
        {
            const float4* hn4 = (const float4*)&hbuf[cur][g][0];
            const float* pA = AT + jl;
            float acc = c1r;
            #pragma unroll 4
            for (int k4 = 0; k4 < 32; ++k4){
                float4 hv = hn4[k4];
                acc = fmaf(pA[(4*k4+0)*128], hv.x, acc);
                acc = fmaf(pA[(4*k4+1)*128], hv.y, acc);
                acc = fmaf(pA[(4*k4+2)*128], hv.z, acc);
                acc = fmaf(pA[(4*k4+3)*128], hv.w, acc);
            }
            ahl[g][jl] = acc;
        }
        __syncthreads();                           // B3: ahl visible
        // ---- phase 3: attention scores; no-max softmax (|sc| <= ~28) ----
        const float4* ah4 = (const float4*)&ahl[g][0];
        float sc = 0.f;
        #pragma unroll 2
        for (int k = 0; k < 32; ++k){
            float4 ah = ah4[k];
            { float4 a = A4g[4*k+0]; float tt = fmaf(a.x,s0n, fmaf(a.y,s1n, fmaf(a.z,d0n, ah.x))); sc = fmaf(tanh_ps(tt), a.w, sc); }
            { float4 a = A4g[4*k+1]; float tt = fmaf(a.x,s0n, fmaf(a.y,s1n, fmaf(a.z,d0n, ah.y))); sc = fmaf(tanh_ps(tt), a.w, sc); }
            { float4 a = A4g[4*k+2]; float tt = fmaf(a.x,s0n, fmaf(a.y,s1n, fmaf(a.z,d0n, ah.z))); sc = fmaf(tanh_ps(tt), a.w, sc); }
            { float4 a = A4g[4*k+3]; float tt = fmaf(a.x,s0n, fmaf(a.y,s1n, fmaf(a.z,d0n, ah.w))); sc = fmaf(tanh_ps(tt), a.w, sc); }
        }
        float e  = __expf(sc);
        float se = e, sa = e * s0n, sb = e * s1n;
        #pragma unroll
        for (int off = 32; off > 0; off >>= 1){
            se += __shfl_xor(se, off, 64);
            sa += __shfl_xor(sa, off, 64);
            sb += __shfl_xor(sb, off, 64);
        }
        if ((tid & 63) == 0){ red[g][wv][0]=se; red[g][wv][1]=sa; red[g][wv][2]=sb; }
        __syncthreads();                           // B4: attn partials visible
        {
            float ssum = red[g][0][0] + red[g][1][0];
            float sat  = red[g][0][1] + red[g][1][1];
            float sbt  = red[g][0][2] + red[g][1][2];
            float cs0 = sat / ssum;
            float cs1 = sbt / ssum;
            chl[g][jl] = fmaf(q0r, cs0, fmaf(q1r, cs1, c2r));   // SC*(dec_W2@context fold)
        }
        __syncthreads();                           // B5: chl visible
        // ---- phase 4: decoder scores + argmax + logsumexp ----
        const float4* ch4 = (const float4*)&chl[g][0];
        float lg = 0.f;
        #pragma unroll 2
        for (int k = 0; k < 32; ++k){
            float4 ch = ch4[k];
            { float4 dd = D4g[4*k+0]; float tt = fmaf(dd.x,s0n, fmaf(dd.y,s1n, ch.x)); lg = fmaf(tanh_ps(tt), dd.z, lg); }
            { float4 dd = D4g[4*k+1]; float tt = fmaf(dd.x,s0n, fmaf(dd.y,s1n, ch.y)); lg = fmaf(tanh_ps(tt), dd.z, lg); }
            { float4 dd = D4g[4*k+2]; float tt = fmaf(dd.x,s0n, fmaf(dd.y,s1n, ch.z)); lg = fmaf(tanh_ps(tt), dd.z, lg); }
            { float4 dd = D4g[4*k+3]; float tt = fmaf(dd.x,s0n, fmaf(dd.y,s1n, ch.w)); lg = fmaf(tanh_ps(tt), dd.z, lg); }
        }
        float v = lg; int bi = jl;
        #pragma unroll
        for (int off = 32; off > 0; off >>= 1){   // first-index tie-break == jnp.argmax
            float ov = __shfl_xor(v, off, 64);
            int   oi = __shfl_xor(bi, off, 64);
            if (ov > v || (ov == v && oi < bi)){ v = ov; bi = oi; }
        }
        float e2 = __expf(lg - v);
        #pragma unroll
        for (int off = 32; off > 0; off >>= 1) e2 += __shfl_xor(e2, off, 64);
        if ((tid & 63) == 0){ red[g][wv][4]=v; red[g][wv][5]=__int_as_float(bi); red[g][wv][6]=e2; }
        __syncthreads();                           // B6: argmax partials visible
        int ptrs[2];
        #pragma unroll
        for (int gg = 0; gg < 2; ++gg){
            float va = red[gg][0][4], vb = red[gg][1][4];
            int   ia = __float_as_int(red[gg][0][5]), ib = __float_as_int(red[gg][1][5]);
            ptrs[gg] = (va > vb || (va == vb && ia < ib)) ? ia : ib;
        }
        {   // own-batch logp
            float va = red[g][0][4], vb = red[g][1][4];
            int   ia = __float_as_int(red[g][0][5]), ib = __float_as_int(red[g][1][5]);
            float s2a = red[g][0][6], s2b = red[g][1][6];
            float m2; int ptr;
            if (va > vb || (va == vb && ia < ib)){ m2 = va; ptr = ia; } else { m2 = vb; ptr = ib; }
            float sum2 = fmaf(s2a, __expf(va - m2), s2b * __expf(vb - m2));
            logp -= logf(sum2);
            if (jl == 0) out[b*N128 + t] = (float)ptr;
        }
        l00 = s0l[0][ptrs[0]]; l01 = s1l[0][ptrs[0]];
        l10 = s0l[1][ptrs[1]]; l11 = s1l[1][ptrs[1]];
    }
    if (jl == 0) out[B1024*N128 + b] = logp;
}

extern "C" void kernel_launch(void* const* d_in, const int* in_sizes, int n_in,
                              void* d_out, int out_size, void* d_ws, size_t ws_size,
                              hipStream_t stream)
{
    const float* statc   = (const float*)d_in[0];
    const float* dyn     = (const float*)d_in[1];
    const float* enc_s_w = (const float*)d_in[2];
    const float* enc_s_b = (const float*)d_in[3];
    const float* enc_d_w = (const float*)d_in[4];
    const float* enc_d_b = (const float*)d_in[5];
    const float* x0      = (const float*)d_in[6];
    const float* emb_w   = (const float*)d_in[7];
    const float* emb_b   = (const float*)d_in[8];
    const float* w_ih    = (const float*)d_in[9];
    const float* w_hh    = (const float*)d_in[10];
    const float* b_ih    = (const float*)d_in[11];
    const float* b_hh    = (const float*)d_in[12];
    const float* attn_v  = (const float*)d_in[13];
    const float* attn_W  = (const float*)d_in[14];
    const float* dec_v   = (const float*)d_in[15];
    const float* dec_W   = (const float*)d_in[16];

    float* ws = (float*)d_ws;
    float4* A4 = (float4*)(ws);
    float4* D4 = (float4*)(ws + 512);
    float4* Q4 = (float4*)(ws + 1024);
    float4* G4 = (float4*)(ws + 1536);
    float*  WT = ws + 3072;            // [128][384]
    float*  AT = ws + 3072 + 49152;    // [128][128], pre-scaled by SC

    prep_kernel<<<dim3(4), dim3(128), 0, stream>>>(
        enc_s_w, enc_s_b, enc_d_w, enc_d_b, emb_w, emb_b,
        w_ih, b_ih, b_hh, attn_v, attn_W, dec_v, dec_W,
        A4, D4, Q4, G4);

    tp_kernel<<<dim3(256), dim3(256), 0, stream>>>(w_hh, attn_W, WT, AT);

    decode_kernel<<<dim3(B1024/2), dim3(256), 0, stream>>>(
        statc, dyn, x0, WT, AT,
        A4, D4, Q4, G4, (float*)d_out);
}

// Round 11
// 2735.063 us; speedup vs baseline: 2.1931x; 1.0074x over previous
//
#include <hip/hip_runtime.h>

// DRL4TSP pointer-network decode. B=1024, S=2, D=1, H=128, N=128.
// Rank-collapse algebra: static_enc rank-2+bias, dynamic_enc rank-1+bias =>
// all big per-step GEMMs become precomputed H-vectors + w_hh@h, A3@h matvecs
// + two HxN tanh-dot loops.
//
// R9 (3rd submission; R9/R10 attempts hit GPU-acquisition timeouts):
// R8 measured per-SIMD issue ~19% with 2 waves/SIMD (grid-limited
// 8 waves/CU) -- latency-bound on L2 weight loads inside serialized phases.
// Restructure: 512-thread blocks, 2 batches, k-SPLIT parallelism (half/quarter
// dots combined via LDS partials) -> 16 waves/CU = 4 waves/SIMD, per-wave work
// halved, weight traffic unchanged (loads still serve both batches).
// C-threads (tid<256, 1 wave/SIMD) own combine/softmax/argmax phases.
// Kept validated numerics: tanh_ps, SC-folded tables, no-max attn softmax.

#define H128 128
#define N128 128
#define B1024 1024
#define SC 2.885390081777927f   // 2*log2(e): tanh(x) = 1 - 2/(exp2(SC*x)+1)

__device__ __forceinline__ float sigmoid_acc(float x){
    return 1.f / (1.f + expf(-x));
}
// pre-scaled fast tanh: input already multiplied by SC (folded into tables).
__device__ __forceinline__ float tanh_ps(float xs){
    float e = exp2f(xs);                         // v_exp_f32
    float r = __builtin_amdgcn_rcpf(e + 1.f);    // v_rcp_f32
    return fmaf(-2.f, r, 1.f);
}

// ---------------- prep: fold rank structure into packed tables ----------------
// ws floats: A4[512]@0, D4[512]@512, Q4[512]@1024, G4[1536]@1536,
//            WT[49152]@3072 (w_hh^T: WT[k*384+r]), AT[16384]@52224 (SC*A3^T)
__global__ void prep_kernel(const float* __restrict__ enc_s_w, const float* __restrict__ enc_s_b,
                            const float* __restrict__ enc_d_w, const float* __restrict__ enc_d_b,
                            const float* __restrict__ emb_w,   const float* __restrict__ emb_b,
                            const float* __restrict__ w_ih,    const float* __restrict__ b_ih,
                            const float* __restrict__ b_hh,
                            const float* __restrict__ attn_v,  const float* __restrict__ attn_W,
                            const float* __restrict__ dec_v,   const float* __restrict__ dec_W,
                            float4* __restrict__ A4, float4* __restrict__ D4,
                            float4* __restrict__ Q4, float4* __restrict__ G4)
{
    const int tid = threadIdx.x;
    const int blk = blockIdx.x;
    if (blk < 3){
        const int j = blk*128 + tid;
        const float* w = w_ih + j*H128;
        float a = 0.f, b = 0.f, c = 0.f;
        for (int k = 0; k < H128; ++k){
            float wv = w[k];
            a = fmaf(wv, emb_w[2*k],   a);
            b = fmaf(wv, emb_w[2*k+1], b);
            c = fmaf(wv, emb_b[k],     c);
        }
        G4[j] = make_float4(a, b, c + b_ih[j], b_hh[j]);
    } else {
        const int h = tid;
        const float* aw = attn_W + h*384;
        float u0=0.f, u1=0.f, u2=0.f, c1=0.f;
        for (int k = 0; k < H128; ++k){
            float w = aw[k];
            u0 = fmaf(w, enc_s_w[2*k],   u0);
            u1 = fmaf(w, enc_s_w[2*k+1], u1);
            c1 = fmaf(w, enc_s_b[k],     c1);
        }
        for (int k = 0; k < H128; ++k){
            float w = aw[128+k];
            u2 = fmaf(w, enc_d_w[k], u2);
            c1 = fmaf(w, enc_d_b[k], c1);
        }
        A4[h] = make_float4(SC*u0, SC*u1, SC*u2, attn_v[h]);
        const float* dw = dec_W + h*256;
        float v0=0.f, v1=0.f, c2=0.f, q0=0.f, q1=0.f;
        for (int k = 0; k < H128; ++k){
            float w = dw[k];
            v0 = fmaf(w, enc_s_w[2*k],   v0);
            v1 = fmaf(w, enc_s_w[2*k+1], v1);
            c2 = fmaf(w, enc_s_b[k],     c2);
        }
        for (int k = 0; k < H128; ++k){
            float w = dw[128+k];
            q0 = fmaf(w, enc_s_w[2*k],   q0);
            q1 = fmaf(w, enc_s_w[2*k+1], q1);
            c2 = fmaf(w, enc_s_b[k],     c2);   // ctx bias == enc_s_b (sum attn == 1)
        }
        D4[h] = make_float4(SC*v0, SC*v1, dec_v[h], 0.f);
        Q4[h] = make_float4(SC*q0, SC*q1, SC*c2, SC*c1);
    }
}

// one-time weight transpose (AT pre-scaled by SC)
__global__ void tp_kernel(const float* __restrict__ whh, const float* __restrict__ attnW,
                          float* __restrict__ WT, float* __restrict__ AT)
{
    const int idx = blockIdx.x*256 + threadIdx.x;
    if (idx < 49152){
        const int k = idx / 384, r = idx - k*384;   // WT[k][r] = whh[r][k]
        WT[idx] = whh[r*H128 + k];
    } else {
        const int i2 = idx - 49152;                  // AT[k][j] = SC*attn_W[j][256+k]
        const int k = i2 >> 7, j = i2 & 127;
        AT[i2] = SC * attnW[j*384 + 256 + k];
    }
}

// ---------------- main decode: one block = 2 batches, 512 threads ----------------
__global__ __launch_bounds__(512, 4)
void decode_kernel(const float* __restrict__ statc, const float* __restrict__ dyn,
                   const float* __restrict__ x0,
                   const float* __restrict__ WT, const float* __restrict__ AT,
                   const float4* __restrict__ A4g, const float4* __restrict__ D4g,
                   const float4* __restrict__ Q4g, const float4* __restrict__ G4g,
                   float* __restrict__ out)
{
    __shared__ __align__(16) float hbuf[2][2][H128];   // [pingpong][g][h]
    __shared__ float gprz[2][2][256];                  // [g][k-half][row 0-255] r/z partials
    __shared__ float gprn[2][4][H128];                 // [g][k-quarter][row] n partials
    __shared__ float ahp[2][4][H128];                  // [g][k-quarter][j] A3 partials
    __shared__ __align__(16) float ahl[2][H128];
    __shared__ __align__(16) float chl[2][H128];
    __shared__ float scp[2][2][H128];                  // [g][h-half][n] score partials (P3/P4 reuse)
    __shared__ float s0l[2][N128], s1l[2][N128];
    __shared__ float red[2][2][8];

    const int tid = threadIdx.x;
    // main-role indices (all 512 threads)
    const int mg  = tid >> 8;          // batch for P3/P4 scores
    const int mn  = tid & 127;         // column / row-within-128
    const int hi  = (tid >> 7) & 1;    // h-half for P3/P4
    const int q   = (tid >> 7) & 3;    // k-quarter for P1-n / P2
    const int rowa  = tid & 255;       // P1 r/z row (0-127 = r, 128-255 = z)
    const int halfa = mg;              // P1 r/z k-half
    const int b0  = blockIdx.x*2;

    const float s0n = statc[(b0+mg)*256 + mn];
    const float s1n = statc[(b0+mg)*256 + 128 + mn];
    const float d0n = dyn[(b0+mg)*128 + mn];
    s0l[mg][mn] = s0n; s1l[mg][mn] = s1n;   // duplicate write across hi: harmless

    // C-role (tid<256): cg = batch, cn = h-index / column. One wave per SIMD.
    const int cg = tid >> 7;
    const int cn = tid & 127;
    const int wvi = (tid >> 6) & 1;    // wave-within-cg for red[]
    float4 Gr = make_float4(0,0,0,0), Gz = Gr, Gn = Gr, qv = Gr;
    float cs0n = 0.f, cs1n = 0.f, hreg = 0.f, lA = 0.f, lB = 0.f, logp = 0.f;
    if (tid < 256){
        Gr = G4g[cn]; Gz = G4g[128+cn]; Gn = G4g[256+cn];
        qv = Q4g[cn];
        cs0n = statc[(b0+cg)*256 + cn];
        cs1n = statc[(b0+cg)*256 + 128 + cn];
        hbuf[0][cg][cn] = 0.f;
        lA = x0[0]; lB = x0[1];
    }

    int cur = 0;
    __syncthreads();

    for (int t = 0; t < N128; ++t){
        // ---- P1: w_hh@h partial dots (transposed/coalesced, unroll 4) ----
        const float4* h0v = (const float4*)&hbuf[cur][0][0];
        const float4* h1v = (const float4*)&hbuf[cur][1][0];
        {   // r/z half-dot: row rowa, k in [halfa*64, +64)
            const float* pW = WT + rowa;
            float a0 = 0.f, a1 = 0.f;
            #pragma unroll 4
            for (int ki = 0; ki < 16; ++ki){
                const int k4 = halfa*16 + ki;
                float4 h0 = h0v[k4], h1 = h1v[k4];
                float w0 = pW[(4*k4+0)*384];
                float w1 = pW[(4*k4+1)*384];
                float w2 = pW[(4*k4+2)*384];
                float w3 = pW[(4*k4+3)*384];
                a0 = fmaf(w0,h0.x, fmaf(w1,h0.y, fmaf(w2,h0.z, fmaf(w3,h0.w, a0))));
                a1 = fmaf(w0,h1.x, fmaf(w1,h1.y, fmaf(w2,h1.z, fmaf(w3,h1.w, a1))));
            }
            gprz[0][halfa][rowa] = a0;
            gprz[1][halfa][rowa] = a1;
        }
        {   // n-gate quarter-dot: row mn, k in [q*32, +32)
            const float* pW = WT + 256 + mn;
            float a0 = 0.f, a1 = 0.f;
            #pragma unroll 4
            for (int ki = 0; ki < 8; ++ki){
                const int k4 = q*8 + ki;
                float4 h0 = h0v[k4], h1 = h1v[k4];
                float w0 = pW[(4*k4+0)*384];
                float w1 = pW[(4*k4+1)*384];
                float w2 = pW[(4*k4+2)*384];
                float w3 = pW[(4*k4+3)*384];
                a0 = fmaf(w0,h0.x, fmaf(w1,h0.y, fmaf(w2,h0.z, fmaf(w3,h0.w, a0))));
                a1 = fmaf(w0,h1.x, fmaf(w1,h1.y, fmaf(w2,h1.z, fmaf(w3,h1.w, a1))));
            }
            gprn[0][q][mn] = a0;
            gprn[1][q][mn] = a1;
        }
        __syncthreads();                           // B1: partials visible
        // ---- GRU combine (C-threads). libm numerics on h path. ----
        if (tid < 256){
            float accr = gprz[cg][0][cn]     + gprz[cg][1][cn];
            float accz = gprz[cg][0][128+cn] + gprz[cg][1][128+cn];
            float accn = (gprn[cg][0][cn]+gprn[cg][1][cn]) + (gprn[cg][2][cn]+gprn[cg][3][cn]);
            float gir = fmaf(Gr.x, lA, fmaf(Gr.y, lB, Gr.z));
            float giz = fmaf(Gz.x, lA, fmaf(Gz.y, lB, Gz.z));
            float gin = fmaf(Gn.x, lA, fmaf(Gn.y, lB, Gn.z));
            float r  = sigmoid_acc(gir + (accr + Gr.w));
            float z  = sigmoid_acc(giz + (accz + Gz.w));
            float nn = tanhf(gin + r * (accn + Gn.w));
            float hnew = (1.f - z) * nn + z * hreg;
            hbuf[cur^1][cg][cn] = hnew; hreg = hnew;
        }
        __syncthreads();                           // B2: new h visible
        cur ^= 1;
        // ---- P2: A3@h quarter-dots ----
        {
            const float4* hn0 = (const float4*)&hbuf[cur][0][0];
            const float4* hn1 = (const float4*)&hbuf[cur][1][0];
            const float* pA = AT + mn;
            float a0 = 0.f, a1 = 0.f;
            #pragma unroll 4
            for (int ki = 0; ki < 8; ++ki){
                const int k4 = q*8 + ki;
                float4 hv0 = hn0[k4], hv1 = hn1[k4];
                float w0 = pA[(4*k4+0)*128];
                float w1 = pA[(4*k4+1)*128];
                float w2 = pA[(4*k4+2)*128];
                float w3 = pA[(4*k4+3)*128];
                a0 = fmaf(w0,hv0.x, fmaf(w1,hv0.y, fmaf(w2,hv0.z, fmaf(w3,hv0.w, a0))));
                a1 = fmaf(w0,hv1.x, fmaf(w1,hv1.y, fmaf(w2,hv1.z, fmaf(w3,hv1.w, a1))));
            }
            ahp[0][q][mn] = a0;
            ahp[1][q][mn] = a1;
        }
        __syncthreads();                           // B3: ahp visible
        if (tid < 256){
            ahl[cg][cn] = ((ahp[cg][0][cn]+ahp[cg][1][cn]) + (ahp[cg][2][cn]+ahp[cg][3][cn])) + qv.w;
        }
        __syncthreads();                           // B3b: ahl visible
        // ---- P3: attention score half-dots (thread = (mg, mn, hi)) ----
        {
            const float4* ah4 = (const float4*)&ahl[mg][0];
            float sc = 0.f;
            #pragma unroll 2
            for (int kk = 0; kk < 16; ++kk){
                const int k = hi*16 + kk;
                float4 ah = ah4[k];
                { float4 a = A4g[4*k+0]; float tt = fmaf(a.x,s0n, fmaf(a.y,s1n, fmaf(a.z,d0n, ah.x))); sc = fmaf(tanh_ps(tt), a.w, sc); }
                { float4 a = A4g[4*k+1]; float tt = fmaf(a.x,s0n, fmaf(a.y,s1n, fmaf(a.z,d0n, ah.y))); sc = fmaf(tanh_ps(tt), a.w, sc); }
                { float4 a = A4g[4*k+2]; float tt = fmaf(a.x,s0n, fmaf(a.y,s1n, fmaf(a.z,d0n, ah.z))); sc = fmaf(tanh_ps(tt), a.w, sc); }
                { float4 a = A4g[4*k+3]; float tt = fmaf(a.x,s0n, fmaf(a.y,s1n, fmaf(a.z,d0n, ah.w))); sc = fmaf(tanh_ps(tt), a.w, sc); }
            }
            scp[mg][hi][mn] = sc;
        }
        __syncthreads();                           // B4a: score partials visible
        if (tid < 256){   // no-max softmax (|sc| <= ~28): exp + wave reduce
            float sc = scp[cg][0][cn] + scp[cg][1][cn];
            float e  = __expf(sc);
            float se = e, sa = e * cs0n, sb = e * cs1n;
            #pragma unroll
            for (int off = 32; off > 0; off >>= 1){
                se += __shfl_xor(se, off, 64);
                sa += __shfl_xor(sa, off, 64);
                sb += __shfl_xor(sb, off, 64);
            }
            if ((tid & 63) == 0){ red[cg][wvi][0]=se; red[cg][wvi][1]=sa; red[cg][wvi][2]=sb; }
        }
        __syncthreads();                           // B4b: attn partials visible
        if (tid < 256){
            float ssum = red[cg][0][0] + red[cg][1][0];
            float sat  = red[cg][0][1] + red[cg][1][1];
            float sbt  = red[cg][0][2] + red[cg][1][2];
            float cs0 = sat / ssum;
            float cs1 = sbt / ssum;
            chl[cg][cn] = fmaf(qv.x, cs0, fmaf(qv.y, cs1, qv.z));   // SC*(dec_W2@ctx fold)
        }
        __syncthreads();                           // B5: chl visible
        // ---- P4: decoder score half-dots ----
        {
            const float4* ch4 = (const float4*)&chl[mg][0];
            float lg = 0.f;
            #pragma unroll 2
            for (int kk = 0; kk < 16; ++kk){
                const int k = hi*16 + kk;
                float4 ch = ch4[k];
                { float4 dd = D4g[4*k+0]; float tt = fmaf(dd.x,s0n, fmaf(dd.y,s1n, ch.x)); lg = fmaf(tanh_ps(tt), dd.z, lg); }
                { float4 dd = D4g[4*k+1]; float tt = fmaf(dd.x,s0n, fmaf(dd.y,s1n, ch.y)); lg = fmaf(tanh_ps(tt), dd.z, lg); }
                { float4 dd = D4g[4*k+2]; float tt = fmaf(dd.x,s0n, fmaf(dd.y,s1n, ch.z)); lg = fmaf(tanh_ps(tt), dd.z, lg); }
                { float4 dd = D4g[4*k+3]; float tt = fmaf(dd.x,s0n, fmaf(dd.y,s1n, ch.w)); lg = fmaf(tanh_ps(tt), dd.z, lg); }
            }
            scp[mg][hi][mn] = lg;                  // reuse scp (prior reads all pre-B5)
        }
        __syncthreads();                           // B6a: decoder partials visible
        if (tid < 256){   // argmax + logsumexp, wave-level
            float lg = scp[cg][0][cn] + scp[cg][1][cn];
            float v = lg; int bi = cn;
            #pragma unroll
            for (int off = 32; off > 0; off >>= 1){   // first-index tie-break == jnp.argmax
                float ov = __shfl_xor(v, off, 64);
                int   oi = __shfl_xor(bi, off, 64);
                if (ov > v || (ov == v && oi < bi)){ v = ov; bi = oi; }
            }
            float e2 = __expf(lg - v);
            #pragma unroll
            for (int off = 32; off > 0; off >>= 1) e2 += __shfl_xor(e2, off, 64);
            if ((tid & 63) == 0){ red[cg][wvi][4]=v; red[cg][wvi][5]=__int_as_float(bi); red[cg][wvi][6]=e2; }
        }
        __syncthreads();                           // B6b: argmax partials visible
        if (tid < 256){
            float va = red[cg][0][4], vb = red[cg][1][4];
            int   ia = __float_as_int(red[cg][0][5]), ib = __float_as_int(red[cg][1][5]);
            float s2a = red[cg][0][6], s2b = red[cg][1][6];
            float m2; int ptr;
            if (va > vb || (va == vb && ia < ib)){ m2 = va; ptr = ia; } else { m2 = vb; ptr = ib; }
            float sum2 = fmaf(s2a, __expf(va - m2), s2b * __expf(vb - m2));
            logp -= logf(sum2);                    // log(max prob) = -log(sum exp(l-m))
            if (cn == 0) out[(b0+cg)*N128 + t] = (float)ptr;
            lA = s0l[cg][ptr];                     // last_out = static[b,:,ptr]
            lB = s1l[cg][ptr];
        }
        // next-step LDS writes fenced by B1..B6b; no trailing barrier needed
    }
    if (tid < 256 && cn == 0) out[B1024*N128 + (b0+cg)] = logp;
}

extern "C" void kernel_launch(void* const* d_in, const int* in_sizes, int n_in,
                              void* d_out, int out_size, void* d_ws, size_t ws_size,
                              hipStream_t stream)
{
    const float* statc   = (const float*)d_in[0];
    const float* dyn     = (const float*)d_in[1];
    const float* enc_s_w = (const float*)d_in[2];
    const float* enc_s_b = (const float*)d_in[3];
    const float* enc_d_w = (const float*)d_in[4];
    const float* enc_d_b = (const float*)d_in[5];
    const float* x0      = (const float*)d_in[6];
    const float* emb_w   = (const float*)d_in[7];
    const float* emb_b   = (const float*)d_in[8];
    const float* w_ih    = (const float*)d_in[9];
    const float* w_hh    = (const float*)d_in[10];
    const float* b_ih    = (const float*)d_in[11];
    const float* b_hh    = (const float*)d_in[12];
    const float* attn_v  = (const float*)d_in[13];
    const float* attn_W  = (const float*)d_in[14];
    const float* dec_v   = (const float*)d_in[15];
    const float* dec_W   = (const float*)d_in[16];

    float* ws = (float*)d_ws;
    float4* A4 = (float4*)(ws);
    float4* D4 = (float4*)(ws + 512);
    float4* Q4 = (float4*)(ws + 1024);
    float4* G4 = (float4*)(ws + 1536);
    float*  WT = ws + 3072;            // [128][384]
    float*  AT = ws + 3072 + 49152;    // [128][128], pre-scaled by SC

    prep_kernel<<<dim3(4), dim3(128), 0, stream>>>(
        enc_s_w, enc_s_b, enc_d_w, enc_d_b, emb_w, emb_b,
        w_ih, b_ih, b_hh, attn_v, attn_W, dec_v, dec_W,
        A4, D4, Q4, G4);

    tp_kernel<<<dim3(256), dim3(256), 0, stream>>>(w_hh, attn_W, WT, AT);

    decode_kernel<<<dim3(B1024/2), dim3(512), 0, stream>>>(
        statc, dyn, x0, WT, AT,
        A4, D4, Q4, G4, (float*)d_out);
}

// Round 12
// 2478.701 us; speedup vs baseline: 2.4199x; 1.1034x over previous
//
#include <hip/hip_runtime.h>

// DRL4TSP pointer-network decode. B=1024, S=2, D=1, H=128, N=128.
// Rank-collapse algebra: static_enc rank-2+bias, dynamic_enc rank-1+bias =>
// all big per-step GEMMs become precomputed H-vectors + w_hh@h, A3@h matvecs
// + two HxN tanh-dot loops.
//
// R12: R9 (k-split, 16 waves/CU) was NEUTRAL vs R8 despite 2x occupancy ->
// falsified the TLP-hiding theory. Barrier-locked waves stall together on
// serialized L2 load-group chains (~300cy per unroll-4 group). This round
// removes the mechanism: ALL per-step weights (WT 192KB + AT 64KB = 64K
// floats) live in REGISTERS -- 128 floats/thread at 512 threads -- preloaded
// once, reused across all 128 steps. G=4 batches/block (256 blocks = 1/CU):
// each weight register feeds 4 FMA/step. Phases are now pure FMA + LDS
// broadcasts; 7 barriers/step. P1/P2 math bitwise-identical to R9 (validated
// absmax 0.0); P3/P4 full-column reassociation (~1e-7 class, validated).
// Kept: tanh_ps, SC-folded tables, no-max attn softmax.

#define H128 128
#define N128 128
#define B1024 1024
#define SC 2.885390081777927f   // 2*log2(e): tanh(x) = 1 - 2/(exp2(SC*x)+1)

__device__ __forceinline__ float sigmoid_acc(float x){
    return 1.f / (1.f + expf(-x));
}
// pre-scaled fast tanh: input already multiplied by SC (folded into tables).
__device__ __forceinline__ float tanh_ps(float xs){
    float e = exp2f(xs);                         // v_exp_f32
    float r = __builtin_amdgcn_rcpf(e + 1.f);    // v_rcp_f32
    return fmaf(-2.f, r, 1.f);
}

// ---------------- prep: fold rank structure into packed tables ----------------
// ws floats: A4[512]@0, D4[512]@512, Q4[512]@1024, G4[1536]@1536,
//            WT[49152]@3072 (w_hh^T: WT[k*384+r]), AT[16384]@52224 (SC*A3^T)
__global__ void prep_kernel(const float* __restrict__ enc_s_w, const float* __restrict__ enc_s_b,
                            const float* __restrict__ enc_d_w, const float* __restrict__ enc_d_b,
                            const float* __restrict__ emb_w,   const float* __restrict__ emb_b,
                            const float* __restrict__ w_ih,    const float* __restrict__ b_ih,
                            const float* __restrict__ b_hh,
                            const float* __restrict__ attn_v,  const float* __restrict__ attn_W,
                            const float* __restrict__ dec_v,   const float* __restrict__ dec_W,
                            float4* __restrict__ A4, float4* __restrict__ D4,
                            float4* __restrict__ Q4, float4* __restrict__ G4)
{
    const int tid = threadIdx.x;
    const int blk = blockIdx.x;
    if (blk < 3){
        const int j = blk*128 + tid;
        const float* w = w_ih + j*H128;
        float a = 0.f, b = 0.f, c = 0.f;
        for (int k = 0; k < H128; ++k){
            float wv = w[k];
            a = fmaf(wv, emb_w[2*k],   a);
            b = fmaf(wv, emb_w[2*k+1], b);
            c = fmaf(wv, emb_b[k],     c);
        }
        G4[j] = make_float4(a, b, c + b_ih[j], b_hh[j]);
    } else {
        const int h = tid;
        const float* aw = attn_W + h*384;
        float u0=0.f, u1=0.f, u2=0.f, c1=0.f;
        for (int k = 0; k < H128; ++k){
            float w = aw[k];
            u0 = fmaf(w, enc_s_w[2*k],   u0);
            u1 = fmaf(w, enc_s_w[2*k+1], u1);
            c1 = fmaf(w, enc_s_b[k],     c1);
        }
        for (int k = 0; k < H128; ++k){
            float w = aw[128+k];
            u2 = fmaf(w, enc_d_w[k], u2);
            c1 = fmaf(w, enc_d_b[k], c1);
        }
        A4[h] = make_float4(SC*u0, SC*u1, SC*u2, attn_v[h]);
        const float* dw = dec_W + h*256;
        float v0=0.f, v1=0.f, c2=0.f, q0=0.f, q1=0.f;
        for (int k = 0; k < H128; ++k){
            float w = dw[k];
            v0 = fmaf(w, enc_s_w[2*k],   v0);
            v1 = fmaf(w, enc_s_w[2*k+1], v1);
            c2 = fmaf(w, enc_s_b[k],     c2);
        }
        for (int k = 0; k < H128; ++k){
            float w = dw[128+k];
            q0 = fmaf(w, enc_s_w[2*k],   q0);
            q1 = fmaf(w, enc_s_w[2*k+1], q1);
            c2 = fmaf(w, enc_s_b[k],     c2);   // ctx bias == enc_s_b (sum attn == 1)
        }
        D4[h] = make_float4(SC*v0, SC*v1, dec_v[h], 0.f);
        Q4[h] = make_float4(SC*q0, SC*q1, SC*c2, SC*c1);
    }
}

// one-time weight transpose (AT pre-scaled by SC)
__global__ void tp_kernel(const float* __restrict__ whh, const float* __restrict__ attnW,
                          float* __restrict__ WT, float* __restrict__ AT)
{
    const int idx = blockIdx.x*256 + threadIdx.x;
    if (idx < 49152){
        const int k = idx / 384, r = idx - k*384;   // WT[k][r] = whh[r][k]
        WT[idx] = whh[r*H128 + k];
    } else {
        const int i2 = idx - 49152;                  // AT[k][j] = SC*attn_W[j][256+k]
        const int k = i2 >> 7, j = i2 & 127;
        AT[i2] = SC * attnW[j*384 + 256 + k];
    }
}

// ---------------- main decode: one block = 4 batches, 512 threads ----------------
// Weights persistent in VGPRs: wrz[64] (r/z half-row), wn[32] (n quarter-row),
// wa[32] (A3 quarter-row) = 128 floats/thread. All register-array indices are
// compile-time (full unroll) -- rule: runtime-indexed arrays go to scratch.
__global__ __launch_bounds__(512, 2)
void decode_kernel(const float* __restrict__ statc, const float* __restrict__ dyn,
                   const float* __restrict__ x0,
                   const float* __restrict__ WT, const float* __restrict__ AT,
                   const float4* __restrict__ A4g, const float4* __restrict__ D4g,
                   const float4* __restrict__ Q4g, const float4* __restrict__ G4g,
                   float* __restrict__ out)
{
    __shared__ __align__(16) float hbuf[2][4][H128];   // [pingpong][g][h]
    __shared__ float gprz[4][2][256];                  // [g][k-half][row 0-255] r/z partials
    __shared__ float gprn[4][4][H128];                 // [g][k-quarter][row] n partials
    __shared__ float ahp[4][4][H128];                  // [g][k-quarter][j] A3 partials
    __shared__ __align__(16) float ahl[4][H128];
    __shared__ __align__(16) float chl[4][H128];
    __shared__ float s0l[4][N128], s1l[4][N128];
    __shared__ float red[4][2][8];

    const int tid = threadIdx.x;
    const int cg    = tid >> 7;        // batch 0..3 (combine/P2-quarter/P3/P4 roles)
    const int cn    = tid & 127;       // h-row / column / quarter-row
    const int wvi   = (tid >> 6) & 1;  // wave within the batch's 128 threads
    const int rowa  = tid & 255;       // P1 r/z row (0-127 = r, 128-255 = z)
    const int halfa = tid >> 8;        // P1 r/z k-half
    const int q     = cg;              // k-quarter alias
    const int b0    = blockIdx.x*4;

    // ---- persistent weight registers (preloaded once, coalesced) ----
    float wrz[64], wn[32], wa[32];
    {
        const float* pW = WT + rowa;
        #pragma unroll
        for (int j = 0; j < 64; ++j) wrz[j] = pW[(halfa*64 + j)*384];
        const float* pN = WT + 256 + cn;
        #pragma unroll
        for (int j = 0; j < 32; ++j) wn[j] = pN[(q*32 + j)*384];
        const float* pA = AT + cn;
        #pragma unroll
        for (int j = 0; j < 32; ++j) wa[j] = pA[(q*32 + j)*128];
    }

    const float4 Gr = G4g[cn], Gz = G4g[128+cn], Gn = G4g[256+cn];
    const float4 qv = Q4g[cn];

    const float s0n = statc[(b0+cg)*256 + cn];
    const float s1n = statc[(b0+cg)*256 + 128 + cn];
    const float d0n = dyn[(b0+cg)*128 + cn];
    s0l[cg][cn] = s0n; s1l[cg][cn] = s1n;
    hbuf[0][cg][cn] = 0.f;
    float hreg = 0.f;
    float lA = x0[0], lB = x0[1];      // last_out for this thread's batch cg
    float logp = 0.f;

    int cur = 0;
    __syncthreads();

    for (int t = 0; t < N128; ++t){
        const float4* h0v = (const float4*)&hbuf[cur][0][0];
        const float4* h1v = (const float4*)&hbuf[cur][1][0];
        const float4* h2v = (const float4*)&hbuf[cur][2][0];
        const float4* h3v = (const float4*)&hbuf[cur][3][0];
        // ---- P1 r/z: half-dot from registers, 4 batches per weight ----
        {
            float a0=0.f, a1=0.f, a2=0.f, a3=0.f;
            #pragma unroll
            for (int j4 = 0; j4 < 16; ++j4){
                const int k4 = halfa*16 + j4;
                float4 h0 = h0v[k4], h1 = h1v[k4], h2 = h2v[k4], h3 = h3v[k4];
                float w0 = wrz[4*j4+0], w1 = wrz[4*j4+1], w2 = wrz[4*j4+2], w3 = wrz[4*j4+3];
                a0 = fmaf(w0,h0.x, fmaf(w1,h0.y, fmaf(w2,h0.z, fmaf(w3,h0.w, a0))));
                a1 = fmaf(w0,h1.x, fmaf(w1,h1.y, fmaf(w2,h1.z, fmaf(w3,h1.w, a1))));
                a2 = fmaf(w0,h2.x, fmaf(w1,h2.y, fmaf(w2,h2.z, fmaf(w3,h2.w, a2))));
                a3 = fmaf(w0,h3.x, fmaf(w1,h3.y, fmaf(w2,h3.z, fmaf(w3,h3.w, a3))));
            }
            gprz[0][halfa][rowa] = a0;
            gprz[1][halfa][rowa] = a1;
            gprz[2][halfa][rowa] = a2;
            gprz[3][halfa][rowa] = a3;
        }
        // ---- P1 n: quarter-dot from registers ----
        {
            float a0=0.f, a1=0.f, a2=0.f, a3=0.f;
            #pragma unroll
            for (int j4 = 0; j4 < 8; ++j4){
                const int k4 = q*8 + j4;
                float4 h0 = h0v[k4], h1 = h1v[k4], h2 = h2v[k4], h3 = h3v[k4];
                float w0 = wn[4*j4+0], w1 = wn[4*j4+1], w2 = wn[4*j4+2], w3 = wn[4*j4+3];
                a0 = fmaf(w0,h0.x, fmaf(w1,h0.y, fmaf(w2,h0.z, fmaf(w3,h0.w, a0))));
                a1 = fmaf(w0,h1.x, fmaf(w1,h1.y, fmaf(w2,h1.z, fmaf(w3,h1.w, a1))));
                a2 = fmaf(w0,h2.x, fmaf(w1,h2.y, fmaf(w2,h2.z, fmaf(w3,h2.w, a2))));
                a3 = fmaf(w0,h3.x, fmaf(w1,h3.y, fmaf(w2,h3.z, fmaf(w3,h3.w, a3))));
            }
            gprn[0][q][cn] = a0;
            gprn[1][q][cn] = a1;
            gprn[2][q][cn] = a2;
            gprn[3][q][cn] = a3;
        }
        __syncthreads();                           // B1: partials visible
        // ---- GRU combine: thread (cg, cn). libm numerics on h path. ----
        {
            float accr = gprz[cg][0][cn]     + gprz[cg][1][cn];
            float accz = gprz[cg][0][128+cn] + gprz[cg][1][128+cn];
            float accn = (gprn[cg][0][cn]+gprn[cg][1][cn]) + (gprn[cg][2][cn]+gprn[cg][3][cn]);
            float gir = fmaf(Gr.x, lA, fmaf(Gr.y, lB, Gr.z));
            float giz = fmaf(Gz.x, lA, fmaf(Gz.y, lB, Gz.z));
            float gin = fmaf(Gn.x, lA, fmaf(Gn.y, lB, Gn.z));
            float r  = sigmoid_acc(gir + (accr + Gr.w));
            float z  = sigmoid_acc(giz + (accz + Gz.w));
            float nn = tanhf(gin + r * (accn + Gn.w));
            float hnew = (1.f - z) * nn + z * hreg;
            hbuf[cur^1][cg][cn] = hnew; hreg = hnew;
        }
        __syncthreads();                           // B2: new h visible
        cur ^= 1;
        // ---- P2: A3@h quarter-dots from registers ----
        {
            const float4* n0 = (const float4*)&hbuf[cur][0][0];
            const float4* n1 = (const float4*)&hbuf[cur][1][0];
            const float4* n2 = (const float4*)&hbuf[cur][2][0];
            const float4* n3 = (const float4*)&hbuf[cur][3][0];
            float a0=0.f, a1=0.f, a2=0.f, a3=0.f;
            #pragma unroll
            for (int j4 = 0; j4 < 8; ++j4){
                const int k4 = q*8 + j4;
                float4 h0 = n0[k4], h1 = n1[k4], h2 = n2[k4], h3 = n3[k4];
                float w0 = wa[4*j4+0], w1 = wa[4*j4+1], w2 = wa[4*j4+2], w3 = wa[4*j4+3];
                a0 = fmaf(w0,h0.x, fmaf(w1,h0.y, fmaf(w2,h0.z, fmaf(w3,h0.w, a0))));
                a1 = fmaf(w0,h1.x, fmaf(w1,h1.y, fmaf(w2,h1.z, fmaf(w3,h1.w, a1))));
                a2 = fmaf(w0,h2.x, fmaf(w1,h2.y, fmaf(w2,h2.z, fmaf(w3,h2.w, a2))));
                a3 = fmaf(w0,h3.x, fmaf(w1,h3.y, fmaf(w2,h3.z, fmaf(w3,h3.w, a3))));
            }
            ahp[0][q][cn] = a0;
            ahp[1][q][cn] = a1;
            ahp[2][q][cn] = a2;
            ahp[3][q][cn] = a3;
        }
        __syncthreads();                           // B3: ahp visible
        ahl[cg][cn] = ((ahp[cg][0][cn]+ahp[cg][1][cn]) + (ahp[cg][2][cn]+ahp[cg][3][cn])) + qv.w;
        __syncthreads();                           // B3b: ahl visible
        // ---- P3: attention scores, full column per thread (cg, cn) ----
        {
            const float4* ah4 = (const float4*)&ahl[cg][0];
            float sc = 0.f;
            #pragma unroll 2
            for (int k = 0; k < 32; ++k){
                float4 ah = ah4[k];
                { float4 a = A4g[4*k+0]; float tt = fmaf(a.x,s0n, fmaf(a.y,s1n, fmaf(a.z,d0n, ah.x))); sc = fmaf(tanh_ps(tt), a.w, sc); }
                { float4 a = A4g[4*k+1]; float tt = fmaf(a.x,s0n, fmaf(a.y,s1n, fmaf(a.z,d0n, ah.y))); sc = fmaf(tanh_ps(tt), a.w, sc); }
                { float4 a = A4g[4*k+2]; float tt = fmaf(a.x,s0n, fmaf(a.y,s1n, fmaf(a.z,d0n, ah.z))); sc = fmaf(tanh_ps(tt), a.w, sc); }
                { float4 a = A4g[4*k+3]; float tt = fmaf(a.x,s0n, fmaf(a.y,s1n, fmaf(a.z,d0n, ah.w))); sc = fmaf(tanh_ps(tt), a.w, sc); }
            }
            // no-max softmax (|sc| <= ~28): exp + wave reduce + cross-wave via red
            float e  = __expf(sc);
            float se = e, sa = e * s0n, sb = e * s1n;
            #pragma unroll
            for (int off = 32; off > 0; off >>= 1){
                se += __shfl_xor(se, off, 64);
                sa += __shfl_xor(sa, off, 64);
                sb += __shfl_xor(sb, off, 64);
            }
            if ((tid & 63) == 0){ red[cg][wvi][0]=se; red[cg][wvi][1]=sa; red[cg][wvi][2]=sb; }
        }
        __syncthreads();                           // B4: attn partials visible
        {
            float ssum = red[cg][0][0] + red[cg][1][0];
            float sat  = red[cg][0][1] + red[cg][1][1];
            float sbt  = red[cg][0][2] + red[cg][1][2];
            float cs0 = sat / ssum;
            float cs1 = sbt / ssum;
            chl[cg][cn] = fmaf(qv.x, cs0, fmaf(qv.y, cs1, qv.z));   // SC*(dec_W2@ctx fold)
        }
        __syncthreads();                           // B5: chl visible
        // ---- P4: decoder scores, full column + argmax + logsumexp ----
        {
            const float4* ch4 = (const float4*)&chl[cg][0];
            float lg = 0.f;
            #pragma unroll 2
            for (int k = 0; k < 32; ++k){
                float4 ch = ch4[k];
                { float4 dd = D4g[4*k+0]; float tt = fmaf(dd.x,s0n, fmaf(dd.y,s1n, ch.x)); lg = fmaf(tanh_ps(tt), dd.z, lg); }
                { float4 dd = D4g[4*k+1]; float tt = fmaf(dd.x,s0n, fmaf(dd.y,s1n, ch.y)); lg = fmaf(tanh_ps(tt), dd.z, lg); }
                { float4 dd = D4g[4*k+2]; float tt = fmaf(dd.x,s0n, fmaf(dd.y,s1n, ch.z)); lg = fmaf(tanh_ps(tt), dd.z, lg); }
                { float4 dd = D4g[4*k+3]; float tt = fmaf(dd.x,s0n, fmaf(dd.y,s1n, ch.w)); lg = fmaf(tanh_ps(tt), dd.z, lg); }
            }
            float v = lg; int bi = cn;
            #pragma unroll
            for (int off = 32; off > 0; off >>= 1){   // first-index tie-break == jnp.argmax
                float ov = __shfl_xor(v, off, 64);
                int   oi = __shfl_xor(bi, off, 64);
                if (ov > v || (ov == v && oi < bi)){ v = ov; bi = oi; }
            }
            float e2 = __expf(lg - v);
            #pragma unroll
            for (int off = 32; off > 0; off >>= 1) e2 += __shfl_xor(e2, off, 64);
            if ((tid & 63) == 0){ red[cg][wvi][4]=v; red[cg][wvi][5]=__int_as_float(bi); red[cg][wvi][6]=e2; }
        }
        __syncthreads();                           // B6: argmax partials visible
        {
            float va = red[cg][0][4], vb = red[cg][1][4];
            int   ia = __float_as_int(red[cg][0][5]), ib = __float_as_int(red[cg][1][5]);
            float s2a = red[cg][0][6], s2b = red[cg][1][6];
            float m2; int ptr;
            if (va > vb || (va == vb && ia < ib)){ m2 = va; ptr = ia; } else { m2 = vb; ptr = ib; }
            float sum2 = fmaf(s2a, __expf(va - m2), s2b * __expf(vb - m2));
            logp -= logf(sum2);                    // log(max prob) = -log(sum exp(l-m))
            if (cn == 0) out[(b0+cg)*N128 + t] = (float)ptr;
            lA = s0l[cg][ptr];                     // last_out = static[b,:,ptr]
            lB = s1l[cg][ptr];
        }
        // next-step LDS writes fenced by B1..B6; no trailing barrier needed
    }
    if (cn == 0) out[B1024*N128 + (b0+cg)] = logp;
}

extern "C" void kernel_launch(void* const* d_in, const int* in_sizes, int n_in,
                              void* d_out, int out_size, void* d_ws, size_t ws_size,
                              hipStream_t stream)
{
    const float* statc   = (const float*)d_in[0];
    const float* dyn     = (const float*)d_in[1];
    const float* enc_s_w = (const float*)d_in[2];
    const float* enc_s_b = (const float*)d_in[3];
    const float* enc_d_w = (const float*)d_in[4];
    const float* enc_d_b = (const float*)d_in[5];
    const float* x0      = (const float*)d_in[6];
    const float* emb_w   = (const float*)d_in[7];
    const float* emb_b   = (const float*)d_in[8];
    const float* w_ih    = (const float*)d_in[9];
    const float* w_hh    = (const float*)d_in[10];
    const float* b_ih    = (const float*)d_in[11];
    const float* b_hh    = (const float*)d_in[12];
    const float* attn_v  = (const float*)d_in[13];
    const float* attn_W  = (const float*)d_in[14];
    const float* dec_v   = (const float*)d_in[15];
    const float* dec_W   = (const float*)d_in[16];

    float* ws = (float*)d_ws;
    float4* A4 = (float4*)(ws);
    float4* D4 = (float4*)(ws + 512);
    float4* Q4 = (float4*)(ws + 1024);
    float4* G4 = (float4*)(ws + 1536);
    float*  WT = ws + 3072;            // [128][384]
    float*  AT = ws + 3072 + 49152;    // [128][128], pre-scaled by SC

    prep_kernel<<<dim3(4), dim3(128), 0, stream>>>(
        enc_s_w, enc_s_b, enc_d_w, enc_d_b, emb_w, emb_b,
        w_ih, b_ih, b_hh, attn_v, attn_W, dec_v, dec_W,
        A4, D4, Q4, G4);

    tp_kernel<<<dim3(256), dim3(256), 0, stream>>>(w_hh, attn_W, WT, AT);

    decode_kernel<<<dim3(B1024/4), dim3(512), 0, stream>>>(
        statc, dyn, x0, WT, AT,
        A4, D4, Q4, G4, (float*)d_out);
}